// Round 4
// baseline (7453.404 us; speedup 1.0000x reference)
//
#include <hip/hip_runtime.h>

typedef unsigned short u16;
typedef unsigned int   u32;
typedef _Float16 f16;
typedef _Float16 half2v __attribute__((ext_vector_type(2)));
typedef _Float16 half8v __attribute__((ext_vector_type(8)));
typedef float float4v __attribute__((ext_vector_type(4)));

#define B_  256
#define T_  512
#define I_  64
#define H_  256
#define G_  1024   // 4*H
#define BT_ (B_*T_)

static __device__ __forceinline__ float fdot2u(u32 a, u32 b, float c) {
#if defined(__has_builtin) && __has_builtin(__builtin_amdgcn_fdot2)
  return __builtin_amdgcn_fdot2(__builtin_bit_cast(half2v, a),
                                __builtin_bit_cast(half2v, b), c, false);
#else
  half2v av = __builtin_bit_cast(half2v, a), bv = __builtin_bit_cast(half2v, b);
  return c + (float)av.x * (float)bv.x + (float)av.y * (float)bv.y;
#endif
}

static __device__ __forceinline__ float sig_(float x) {
  return 1.0f / (1.0f + __expf(-x));
}
static __device__ __forceinline__ float tanh_(float x) {
  float ax = fminf(fabsf(x), 15.0f);
  float e  = __expf(2.0f * ax);
  float t  = (e - 1.0f) / (e + 1.0f);
  return copysignf(t, x);
}

// ---------------- small prep kernels ----------------

__global__ void cvt_f16(const float* __restrict__ in, u16* __restrict__ out, int n) {
  int i = blockIdx.x * blockDim.x + threadIdx.x;
  if (i < n) out[i] = __builtin_bit_cast(u16, (f16)in[i]);
}

__global__ void split_w(const float* __restrict__ w, u16* __restrict__ hi,
                        u16* __restrict__ lo, int n) {
  int i = blockIdx.x * blockDim.x + threadIdx.x;
  if (i < n) {
    float v = w[i];
    f16 h = (f16)v;
    float r = v - (float)h;
    hi[i] = __builtin_bit_cast(u16, h);
    lo[i] = __builtin_bit_cast(u16, (f16)r);
  }
}

__global__ void bias_sum(const float* __restrict__ a, const float* __restrict__ b,
                         float* __restrict__ o, int n) {
  int i = blockIdx.x * blockDim.x + threadIdx.x;
  if (i < n) o[i] = a[i] + b[i];
}

// ---------------- f16 MFMA GEMM with weight hi/lo split ----------------
// C[m][n] = sum_k A[m][k] * (Bh[n][k] + Bl[n][k]) + bias[n]
// A rows are remapped: chunk-local row m -> global row (m>>tcl)*T_ + t0 + (m & (Tc-1))
// PERM=1: store column n at position 4*(n&255) + (n>>8) so the scan kernel
// (thread tid owning logical row (tid&3)*256 + (tid>>2)) reads xp coalesced.
template<int BN, int PERM>
__global__ __launch_bounds__(256) void gemm_ws(
    const u16* __restrict__ A, const u16* __restrict__ Bh, const u16* __restrict__ Bl,
    const float* __restrict__ bias, float* __restrict__ C,
    int K, int tcl, int t0, int N)
{
  constexpr int BM = 128, BK = 64, LDT = 72;  // LDT in f16 units (144 B rows, 16B aligned)
  __shared__ u16 As[BM * LDT];
  __shared__ u16 Bhs[BN * LDT];
  __shared__ u16 Bls[BN * LDT];
  const int tid = threadIdx.x, wave = tid >> 6, lane = tid & 63;
  const int m0 = blockIdx.x * BM, n0 = blockIdx.y * BN;
  constexpr int WNT = BN / 32;          // n-tiles per wave (4 for BN=128, 2 for BN=64)
  const int wm0 = (wave >> 1) * 64, wn0 = (wave & 1) * (BN / 2);
  const int tcmask = (1 << tcl) - 1;
  float4v acc[4][WNT];
  for (int i = 0; i < 4; i++)
    for (int j = 0; j < WNT; j++) acc[i][j] = (float4v){0.f, 0.f, 0.f, 0.f};
  const int lrow = lane & 15, lk = (lane >> 4) * 8;

  for (int k0 = 0; k0 < K; k0 += BK) {
    __syncthreads();
    // stage A: 128 rows x 64 f16 (8x 16B units per row)
#pragma unroll
    for (int i = 0; i < 4; i++) {
      int idx = tid + i * 256, row = idx >> 3, u = idx & 7;
      int m = m0 + row;
      int rg = (m >> tcl) * T_ + t0 + (m & tcmask);
      *(uint4*)(As + row * LDT + u * 8) =
          *(const uint4*)(A + (size_t)rg * K + k0 + u * 8);
    }
#pragma unroll
    for (int i = 0; i < WNT; i++) {
      int idx = tid + i * 256, row = idx >> 3, u = idx & 7;
      size_t go = (size_t)(n0 + row) * K + k0 + u * 8;
      *(uint4*)(Bhs + row * LDT + u * 8) = *(const uint4*)(Bh + go);
      *(uint4*)(Bls + row * LDT + u * 8) = *(const uint4*)(Bl + go);
    }
    __syncthreads();
#pragma unroll
    for (int ks = 0; ks < 2; ++ks) {
      int col = ks * 32 + lk;
      half8v af[4];
#pragma unroll
      for (int mt = 0; mt < 4; mt++)
        af[mt] = *(const half8v*)(const void*)(As + (wm0 + mt * 16 + lrow) * LDT + col);
#pragma unroll
      for (int nt = 0; nt < WNT; nt++) {
        half8v bhv = *(const half8v*)(const void*)(Bhs + (wn0 + nt * 16 + lrow) * LDT + col);
        half8v blv = *(const half8v*)(const void*)(Bls + (wn0 + nt * 16 + lrow) * LDT + col);
#pragma unroll
        for (int mt = 0; mt < 4; mt++) {
          acc[mt][nt] = __builtin_amdgcn_mfma_f32_16x16x32_f16(af[mt], bhv, acc[mt][nt], 0, 0, 0);
          acc[mt][nt] = __builtin_amdgcn_mfma_f32_16x16x32_f16(af[mt], blv, acc[mt][nt], 0, 0, 0);
        }
      }
    }
  }
  // epilogue: C/D layout col = lane&15, row = (lane>>4)*4 + reg
  const int crow = (lane >> 4) * 4, ccol = lane & 15;
#pragma unroll
  for (int nt = 0; nt < WNT; nt++) {
    int n = n0 + wn0 + nt * 16 + ccol;
    float bv = bias[n];
    int ns = PERM ? ((n & 255) * 4 + (n >> 8)) : n;
#pragma unroll
    for (int mt = 0; mt < 4; mt++) {
#pragma unroll
      for (int r = 0; r < 4; r++) {
        int m = m0 + wm0 + mt * 16 + crow + r;
        C[(size_t)m * N + ns] = acc[mt][nt][r] + bv;
      }
    }
  }
}

// ---------------- persistent per-batch LSTM scan ----------------
// One block per batch element (256 blocks, 1024 threads, 16 waves, 1 block/CU,
// 4 waves/SIMD). Thread tid owns ONE logical row lr = (tid&3)*256 + (tid>>2)
// of Whh[1024][256]: elems [0,192) in 96 VGPRs, elems [192,256) in LDS at
// physical offset tid*72 (the proven conflict-free layout).
// The 4 gate rows (i,f,g,o) of h-index m = tid>>2 live in lanes 4m..4m+3 of
// one wave -> gate exchange is 3 __shfl_xor, no LDS round-trip, ONE barrier
// per step (h double-buffered in LDS). xp is stored pre-permuted by the GEMM
// so xp loads here are xpb[tt*1024 + tid] (coalesced).
__global__ __launch_bounds__(1024, 1) void lstm_scan(
    const u16* __restrict__ whh, const float* __restrict__ xp,
    u16* __restrict__ hout, float* __restrict__ cst, u16* __restrict__ hst,
    int Tc, int t0)
{
  __shared__ __align__(16) u16 wt[1024 * 72];   // 144 KB tail weights
  __shared__ __align__(16) u32 h2s[2][128];     // double-buffered h (256 f16)
  const int tid = threadIdx.x, b = blockIdx.x;
  const int q = tid & 3, m = tid >> 2;
  const int lr = q * 256 + m;   // logical Whh row

  uint4 wq[24];
  const uint4* g0 = (const uint4*)(whh + (size_t)lr * 256);
#pragma unroll
  for (int i = 0; i < 24; i++) wq[i] = g0[i];
#pragma unroll
  for (int i = 0; i < 8; i++)
    *((uint4*)(wt + (size_t)tid * 72) + i) = g0[24 + i];

  float cc = 0.f;
  if (t0 == 0) {
    if (tid < 128) h2s[0][tid] = 0u;
  } else {
    if (q == 0) cc = cst[(size_t)b * 256 + m];
    if (tid < 128) h2s[0][tid] = ((const u32*)hst)[(size_t)b * 128 + tid];
  }
  __syncthreads();

  const float* xpb = xp + (size_t)b * Tc * 1024;
  float xn = xpb[tid];
  u16* houtb = hout + (size_t)b * T_ * 256 + (size_t)t0 * 256;
  const uint4* wtp = (const uint4*)(wt + (size_t)tid * 72);

  for (int tt = 0; tt < Tc; ++tt) {
    const int rp = tt & 1, wp = rp ^ 1;
    float a = xn;
    if (tt + 1 < Tc) xn = xpb[(size_t)(tt + 1) * 1024 + tid];
    const uint4* hq = (const uint4*)h2s[rp];
#pragma unroll
    for (int kc = 0; kc < 24; ++kc) {
      uint4 hv = hq[kc];
      uint4 w0 = wq[kc];
      a = fdot2u(w0.x, hv.x, a); a = fdot2u(w0.y, hv.y, a);
      a = fdot2u(w0.z, hv.z, a); a = fdot2u(w0.w, hv.w, a);
    }
#pragma unroll
    for (int kc = 0; kc < 8; ++kc) {
      uint4 hv = hq[24 + kc];
      uint4 w0 = wtp[kc];
      a = fdot2u(w0.x, hv.x, a); a = fdot2u(w0.y, hv.y, a);
      a = fdot2u(w0.z, hv.z, a); a = fdot2u(w0.w, hv.w, a);
    }
    // gate exchange within the 4-lane group: lane 4m+q holds gate q of index m
    float x1 = __shfl_xor(a, 1);          // q=0 gets f-pre
    float x2 = __shfl_xor(a, 2);          // q=0 gets g-pre
    float x3 = __shfl_xor(x1, 2);         // q=0 gets o-pre
    if (q == 0) {
      float iv = sig_(a), fv = sig_(x1), gv = tanh_(x2), ov = sig_(x3);
      cc = fv * cc + iv * gv;
      float hv = ov * tanh_(cc);
      u16 hb = __builtin_bit_cast(u16, (f16)hv);
      ((u16*)h2s[wp])[m] = hb;
      houtb[(size_t)tt * 256 + m] = hb;
    }
    __syncthreads();
  }
  if (q == 0) cst[(size_t)b * 256 + m] = cc;
  if (tid < 128) ((u32*)hst)[(size_t)b * 128 + tid] = h2s[Tc & 1][tid];
}

// ---------------- host ----------------

extern "C" void kernel_launch(void* const* d_in, const int* in_sizes, int n_in,
                              void* d_out, int out_size, void* d_ws, size_t ws_size,
                              hipStream_t stream)
{
  const float* x      = (const float*)d_in[0];
  const float* Wih[4] = {(const float*)d_in[1], (const float*)d_in[5],
                         (const float*)d_in[9], (const float*)d_in[13]};
  const float* Whh[4] = {(const float*)d_in[2], (const float*)d_in[6],
                         (const float*)d_in[10], (const float*)d_in[14]};
  const float* bi[4]  = {(const float*)d_in[3], (const float*)d_in[7],
                         (const float*)d_in[11], (const float*)d_in[15]};
  const float* bh[4]  = {(const float*)d_in[4], (const float*)d_in[8],
                         (const float*)d_in[12], (const float*)d_in[16]};
  const float* outW   = (const float*)d_in[17];
  const float* outb   = (const float*)d_in[18];

  char* ws = (char*)d_ws;
  size_t off = 0;
  auto alc = [&](size_t bytes) -> char* {
    char* p = ws + off;
    off = (off + bytes + 255) & ~(size_t)255;
    return p;
  };

  u16* xf  = (u16*)alc((size_t)BT_ * I_ * 2);
  u16* hb0 = (u16*)alc((size_t)BT_ * H_ * 2);
  u16* hb1 = (u16*)alc((size_t)BT_ * H_ * 2);
  int wihn[4] = {G_ * I_, G_ * H_, G_ * H_, G_ * H_};
  u16 *wihH[4], *wihL[4], *whhH[4];
  float* bsum[4];
  for (int l = 0; l < 4; l++) {
    wihH[l] = (u16*)alc((size_t)wihn[l] * 2);
    wihL[l] = (u16*)alc((size_t)wihn[l] * 2);
    whhH[l] = (u16*)alc((size_t)G_ * H_ * 2);
    bsum[l] = (float*)alc((size_t)G_ * 4);
  }
  u16* owH = (u16*)alc((size_t)I_ * H_ * 2);
  u16* owL = (u16*)alc((size_t)I_ * H_ * 2);
  float* cst = (float*)alc((size_t)B_ * H_ * 4);
  u16*   hst = (u16*)alc((size_t)B_ * H_ * 2);

  // choose time-chunk so the fp32 xp buffer fits in the remaining workspace
  int Tc = T_;
  while (Tc > 16 && off + (size_t)B_ * Tc * G_ * 4 + 4096 > ws_size) Tc >>= 1;
  float* xpb = (float*)alc((size_t)B_ * Tc * G_ * 4);
  int tcl = 0;
  while ((1 << tcl) < Tc) tcl++;

  // prep: conversions / splits / bias sums
  {
    int n = BT_ * I_;
    cvt_f16<<<dim3((n + 255) / 256), dim3(256), 0, stream>>>(x, xf, n);
  }
  for (int l = 0; l < 4; l++) {
    split_w<<<dim3((wihn[l] + 255) / 256), dim3(256), 0, stream>>>(Wih[l], wihH[l], wihL[l], wihn[l]);
    cvt_f16<<<dim3((G_ * H_ + 255) / 256), dim3(256), 0, stream>>>(Whh[l], whhH[l], G_ * H_);
    bias_sum<<<dim3(4), dim3(256), 0, stream>>>(bi[l], bh[l], bsum[l], G_);
  }
  split_w<<<dim3((I_ * H_ + 255) / 256), dim3(256), 0, stream>>>(outW, owH, owL, I_ * H_);

  // 4 LSTM layers, chunked over T
  for (int l = 0; l < 4; l++) {
    const u16* Ain = (l == 0) ? xf : ((l == 1) ? hb0 : (l == 2) ? hb1 : hb0);
    u16* Hout = (l & 1) ? hb1 : hb0;
    int K = (l == 0) ? I_ : H_;
    for (int t0 = 0; t0 < T_; t0 += Tc) {
      gemm_ws<128, 1><<<dim3((B_ * Tc) / 128, G_ / 128), dim3(256), 0, stream>>>(
          Ain, wihH[l], wihL[l], bsum[l], xpb, K, tcl, t0, G_);
      lstm_scan<<<dim3(B_), dim3(1024), 0, stream>>>(whhH[l], xpb, Hout, cst, hst, Tc, t0);
    }
  }

  // output projection: [BT,256] x [64,256]^T -> d_out [BT,64]
  gemm_ws<64, 0><<<dim3(BT_ / 128, 1), dim3(256), 0, stream>>>(
      hb1, owH, owL, outb, (float*)d_out, H_, 9, 0, I_);
}

// Round 5
// 5348.302 us; speedup vs baseline: 1.3936x; 1.3936x over previous
//
#include <hip/hip_runtime.h>

typedef unsigned short u16;
typedef unsigned int   u32;
typedef _Float16 f16;
typedef _Float16 half2v __attribute__((ext_vector_type(2)));
typedef _Float16 half8v __attribute__((ext_vector_type(8)));
typedef float float4v __attribute__((ext_vector_type(4)));

#define B_  256
#define T_  512
#define I_  64
#define H_  256
#define G_  1024   // 4*H
#define BT_ (B_*T_)

static __device__ __forceinline__ float fdot2u(u32 a, u32 b, float c) {
#if defined(__has_builtin) && __has_builtin(__builtin_amdgcn_fdot2)
  return __builtin_amdgcn_fdot2(__builtin_bit_cast(half2v, a),
                                __builtin_bit_cast(half2v, b), c, false);
#else
  half2v av = __builtin_bit_cast(half2v, a), bv = __builtin_bit_cast(half2v, b);
  return c + (float)av.x * (float)bv.x + (float)av.y * (float)bv.y;
#endif
}

static __device__ __forceinline__ float sig_(float x) {
  return 1.0f / (1.0f + __expf(-x));
}
static __device__ __forceinline__ float tanh_(float x) {
  float ax = fminf(fabsf(x), 15.0f);
  float e  = __expf(2.0f * ax);
  float t  = (e - 1.0f) / (e + 1.0f);
  return copysignf(t, x);
}

// ---------------- small prep kernels ----------------

__global__ void cvt_f16(const float* __restrict__ in, u16* __restrict__ out, int n) {
  int i = blockIdx.x * blockDim.x + threadIdx.x;
  if (i < n) out[i] = __builtin_bit_cast(u16, (f16)in[i]);
}

__global__ void split_w(const float* __restrict__ w, u16* __restrict__ hi,
                        u16* __restrict__ lo, int n) {
  int i = blockIdx.x * blockDim.x + threadIdx.x;
  if (i < n) {
    float v = w[i];
    f16 h = (f16)v;
    float r = v - (float)h;
    hi[i] = __builtin_bit_cast(u16, h);
    lo[i] = __builtin_bit_cast(u16, (f16)r);
  }
}

__global__ void bias_sum(const float* __restrict__ a, const float* __restrict__ b,
                         float* __restrict__ o, int n) {
  int i = blockIdx.x * blockDim.x + threadIdx.x;
  if (i < n) o[i] = a[i] + b[i];
}

// ---------------- f16 MFMA GEMM with weight hi/lo split ----------------
// C[m][n] = sum_k A[m][k] * (Bh[n][k] + Bl[n][k]) + bias[n]
// A rows are remapped: chunk-local row m -> global row (m>>tcl)*T_ + t0 + (m & (Tc-1))
template<int BN>
__global__ __launch_bounds__(256) void gemm_ws(
    const u16* __restrict__ A, const u16* __restrict__ Bh, const u16* __restrict__ Bl,
    const float* __restrict__ bias, float* __restrict__ C,
    int K, int tcl, int t0, int N)
{
  constexpr int BM = 128, BK = 64, LDT = 72;  // LDT in f16 units (144 B rows, 16B aligned)
  __shared__ u16 As[BM * LDT];
  __shared__ u16 Bhs[BN * LDT];
  __shared__ u16 Bls[BN * LDT];
  const int tid = threadIdx.x, wave = tid >> 6, lane = tid & 63;
  const int m0 = blockIdx.x * BM, n0 = blockIdx.y * BN;
  constexpr int WNT = BN / 32;          // n-tiles per wave (4 for BN=128, 2 for BN=64)
  const int wm0 = (wave >> 1) * 64, wn0 = (wave & 1) * (BN / 2);
  const int tcmask = (1 << tcl) - 1;
  float4v acc[4][WNT];
  for (int i = 0; i < 4; i++)
    for (int j = 0; j < WNT; j++) acc[i][j] = (float4v){0.f, 0.f, 0.f, 0.f};
  const int lrow = lane & 15, lk = (lane >> 4) * 8;

  for (int k0 = 0; k0 < K; k0 += BK) {
    __syncthreads();
    // stage A: 128 rows x 64 f16 (8x 16B units per row)
#pragma unroll
    for (int i = 0; i < 4; i++) {
      int idx = tid + i * 256, row = idx >> 3, u = idx & 7;
      int m = m0 + row;
      int rg = (m >> tcl) * T_ + t0 + (m & tcmask);
      *(uint4*)(As + row * LDT + u * 8) =
          *(const uint4*)(A + (size_t)rg * K + k0 + u * 8);
    }
#pragma unroll
    for (int i = 0; i < WNT; i++) {
      int idx = tid + i * 256, row = idx >> 3, u = idx & 7;
      size_t go = (size_t)(n0 + row) * K + k0 + u * 8;
      *(uint4*)(Bhs + row * LDT + u * 8) = *(const uint4*)(Bh + go);
      *(uint4*)(Bls + row * LDT + u * 8) = *(const uint4*)(Bl + go);
    }
    __syncthreads();
#pragma unroll
    for (int ks = 0; ks < 2; ++ks) {
      int col = ks * 32 + lk;
      half8v af[4];
#pragma unroll
      for (int mt = 0; mt < 4; mt++)
        af[mt] = *(const half8v*)(const void*)(As + (wm0 + mt * 16 + lrow) * LDT + col);
#pragma unroll
      for (int nt = 0; nt < WNT; nt++) {
        half8v bhv = *(const half8v*)(const void*)(Bhs + (wn0 + nt * 16 + lrow) * LDT + col);
        half8v blv = *(const half8v*)(const void*)(Bls + (wn0 + nt * 16 + lrow) * LDT + col);
#pragma unroll
        for (int mt = 0; mt < 4; mt++) {
          acc[mt][nt] = __builtin_amdgcn_mfma_f32_16x16x32_f16(af[mt], bhv, acc[mt][nt], 0, 0, 0);
          acc[mt][nt] = __builtin_amdgcn_mfma_f32_16x16x32_f16(af[mt], blv, acc[mt][nt], 0, 0, 0);
        }
      }
    }
  }
  // epilogue: C/D layout col = lane&15, row = (lane>>4)*4 + reg
  const int crow = (lane >> 4) * 4, ccol = lane & 15;
#pragma unroll
  for (int nt = 0; nt < WNT; nt++) {
    int n = n0 + wn0 + nt * 16 + ccol;
    float bv = bias[n];
#pragma unroll
    for (int mt = 0; mt < 4; mt++) {
#pragma unroll
      for (int r = 0; r < 4; r++) {
        int m = m0 + wm0 + mt * 16 + crow + r;
        C[(size_t)m * N + n] = acc[mt][nt][r] + bv;
      }
    }
  }
}

// ---------------- persistent per-batch LSTM scan ----------------
// One block per batch element (256 blocks, 512 threads, 8 waves, 1 block/CU).
// Thread tid owns rows tid and tid+512 of Whh[1024][256] (f16):
//   elems [0,192) in registers, elems [192,256) in LDS (144 KB).
// h broadcast: instead of every thread reading the full 512 B h from LDS
// (which made R0 LDS-return-BW bound: 384 ds_read_b128/CU/step ~ 4600 cyc),
// each WAVE pulls h once via a per-lane ds_read_b64 (lane l holds h-u32 pair
// 2l/2l+1), then __builtin_amdgcn_readlane broadcasts each u32 through an
// SGPR; fdot2 takes the SGPR operand directly (VOP3P allows 1 SGPR src).
// LDS traffic per step/CU: 8 b64 + 128 b128 (weight tails) ~ 1650 cyc.
__global__ __launch_bounds__(512, 2) void lstm_scan(
    const u16* __restrict__ whh, const float* __restrict__ xp,
    u16* __restrict__ hout, float* __restrict__ cst, u16* __restrict__ hst,
    int Tc, int t0)
{
  __shared__ u16 wt[1024 * 72];   // 144 KB: per-row 64-f16 tail (128 B) + 16 B pad
  __shared__ float gs[1024];      // gate pre-activations
  __shared__ u32 h2s[128];        // h as 256 packed f16
  const int tid = threadIdx.x, b = blockIdx.x;
  const int lane = tid & 63;
  const int r0 = tid, r1 = tid + 512;

  uint4 w0q[24], w1q[24];
  const uint4* g0 = (const uint4*)(whh + (size_t)r0 * 256);
  const uint4* g1 = (const uint4*)(whh + (size_t)r1 * 256);
#pragma unroll
  for (int i = 0; i < 24; i++) { w0q[i] = g0[i]; w1q[i] = g1[i]; }
#pragma unroll
  for (int i = 0; i < 8; i++) {
    *((uint4*)(wt + (size_t)r0 * 72) + i) = g0[24 + i];
    *((uint4*)(wt + (size_t)r1 * 72) + i) = g1[24 + i];
  }

  float cc = 0.f;
  if (t0 == 0) {
    if (tid < 128) h2s[tid] = 0u;
  } else {
    if (tid < 256) cc = cst[(size_t)b * 256 + tid];
    if (tid < 128) h2s[tid] = ((const u32*)hst)[(size_t)b * 128 + tid];
  }
  __syncthreads();

  const float* xpb = xp + (size_t)b * Tc * 1024;
  float xn0 = xpb[r0], xn1 = xpb[r1];
  u16* houtb = hout + (size_t)b * T_ * 256 + (size_t)t0 * 256;
  const uint4* wt0 = (const uint4*)(wt + (size_t)r0 * 72);
  const uint4* wt1 = (const uint4*)(wt + (size_t)r1 * 72);

  for (int tt = 0; tt < Tc; ++tt) {
    float a0 = xn0, a1 = xn1;
    if (tt + 1 < Tc) {
      xn0 = xpb[(size_t)(tt + 1) * 1024 + r0];
      xn1 = xpb[(size_t)(tt + 1) * 1024 + r1];
    }
    // wave-level h pull: lane l holds u32 pair (2l, 2l+1) of h
    uint2 hp = *(const uint2*)(h2s + (lane << 1));
#pragma unroll
    for (int kc = 0; kc < 24; ++kc) {
      u32 h0 = (u32)__builtin_amdgcn_readlane((int)hp.x, 2 * kc);
      u32 h1 = (u32)__builtin_amdgcn_readlane((int)hp.y, 2 * kc);
      u32 h2 = (u32)__builtin_amdgcn_readlane((int)hp.x, 2 * kc + 1);
      u32 h3 = (u32)__builtin_amdgcn_readlane((int)hp.y, 2 * kc + 1);
      uint4 w0 = w0q[kc], w1 = w1q[kc];
      a0 = fdot2u(w0.x, h0, a0); a0 = fdot2u(w0.y, h1, a0);
      a0 = fdot2u(w0.z, h2, a0); a0 = fdot2u(w0.w, h3, a0);
      a1 = fdot2u(w1.x, h0, a1); a1 = fdot2u(w1.y, h1, a1);
      a1 = fdot2u(w1.z, h2, a1); a1 = fdot2u(w1.w, h3, a1);
    }
#pragma unroll
    for (int kc = 0; kc < 8; ++kc) {
      int j = 24 + kc;
      u32 h0 = (u32)__builtin_amdgcn_readlane((int)hp.x, 2 * j);
      u32 h1 = (u32)__builtin_amdgcn_readlane((int)hp.y, 2 * j);
      u32 h2 = (u32)__builtin_amdgcn_readlane((int)hp.x, 2 * j + 1);
      u32 h3 = (u32)__builtin_amdgcn_readlane((int)hp.y, 2 * j + 1);
      uint4 w0 = wt0[kc], w1 = wt1[kc];
      a0 = fdot2u(w0.x, h0, a0); a0 = fdot2u(w0.y, h1, a0);
      a0 = fdot2u(w0.z, h2, a0); a0 = fdot2u(w0.w, h3, a0);
      a1 = fdot2u(w1.x, h0, a1); a1 = fdot2u(w1.y, h1, a1);
      a1 = fdot2u(w1.z, h2, a1); a1 = fdot2u(w1.w, h3, a1);
    }
    gs[r0] = a0; gs[r1] = a1;
    __syncthreads();
    if (tid < 256) {
      float gi = gs[tid], gf = gs[tid + 256], gg = gs[tid + 512], go = gs[tid + 768];
      float iv = sig_(gi), fv = sig_(gf), ov = sig_(go), gv = tanh_(gg);
      cc = fv * cc + iv * gv;
      float hv = ov * tanh_(cc);
      u16 hb = __builtin_bit_cast(u16, (f16)hv);
      ((u16*)h2s)[tid] = hb;
      houtb[(size_t)tt * 256 + tid] = hb;
    }
    __syncthreads();
  }
  if (tid < 256) cst[(size_t)b * 256 + tid] = cc;
  if (tid < 128) ((u32*)hst)[(size_t)b * 128 + tid] = h2s[tid];
}

// ---------------- host ----------------

extern "C" void kernel_launch(void* const* d_in, const int* in_sizes, int n_in,
                              void* d_out, int out_size, void* d_ws, size_t ws_size,
                              hipStream_t stream)
{
  const float* x      = (const float*)d_in[0];
  const float* Wih[4] = {(const float*)d_in[1], (const float*)d_in[5],
                         (const float*)d_in[9], (const float*)d_in[13]};
  const float* Whh[4] = {(const float*)d_in[2], (const float*)d_in[6],
                         (const float*)d_in[10], (const float*)d_in[14]};
  const float* bi[4]  = {(const float*)d_in[3], (const float*)d_in[7],
                         (const float*)d_in[11], (const float*)d_in[15]};
  const float* bh[4]  = {(const float*)d_in[4], (const float*)d_in[8],
                         (const float*)d_in[12], (const float*)d_in[16]};
  const float* outW   = (const float*)d_in[17];
  const float* outb   = (const float*)d_in[18];

  char* ws = (char*)d_ws;
  size_t off = 0;
  auto alc = [&](size_t bytes) -> char* {
    char* p = ws + off;
    off = (off + bytes + 255) & ~(size_t)255;
    return p;
  };

  u16* xf  = (u16*)alc((size_t)BT_ * I_ * 2);
  u16* hb0 = (u16*)alc((size_t)BT_ * H_ * 2);
  u16* hb1 = (u16*)alc((size_t)BT_ * H_ * 2);
  int wihn[4] = {G_ * I_, G_ * H_, G_ * H_, G_ * H_};
  u16 *wihH[4], *wihL[4], *whhH[4];
  float* bsum[4];
  for (int l = 0; l < 4; l++) {
    wihH[l] = (u16*)alc((size_t)wihn[l] * 2);
    wihL[l] = (u16*)alc((size_t)wihn[l] * 2);
    whhH[l] = (u16*)alc((size_t)G_ * H_ * 2);
    bsum[l] = (float*)alc((size_t)G_ * 4);
  }
  u16* owH = (u16*)alc((size_t)I_ * H_ * 2);
  u16* owL = (u16*)alc((size_t)I_ * H_ * 2);
  float* cst = (float*)alc((size_t)B_ * H_ * 4);
  u16*   hst = (u16*)alc((size_t)B_ * H_ * 2);

  // choose time-chunk so the fp32 xp buffer fits in the remaining workspace
  int Tc = T_;
  while (Tc > 16 && off + (size_t)B_ * Tc * G_ * 4 + 4096 > ws_size) Tc >>= 1;
  float* xpb = (float*)alc((size_t)B_ * Tc * G_ * 4);
  int tcl = 0;
  while ((1 << tcl) < Tc) tcl++;

  // prep: conversions / splits / bias sums
  {
    int n = BT_ * I_;
    cvt_f16<<<dim3((n + 255) / 256), dim3(256), 0, stream>>>(x, xf, n);
  }
  for (int l = 0; l < 4; l++) {
    split_w<<<dim3((wihn[l] + 255) / 256), dim3(256), 0, stream>>>(Wih[l], wihH[l], wihL[l], wihn[l]);
    cvt_f16<<<dim3((G_ * H_ + 255) / 256), dim3(256), 0, stream>>>(Whh[l], whhH[l], G_ * H_);
    bias_sum<<<dim3(4), dim3(256), 0, stream>>>(bi[l], bh[l], bsum[l], G_);
  }
  split_w<<<dim3((I_ * H_ + 255) / 256), dim3(256), 0, stream>>>(outW, owH, owL, I_ * H_);

  // 4 LSTM layers, chunked over T
  for (int l = 0; l < 4; l++) {
    const u16* Ain = (l == 0) ? xf : ((l == 1) ? hb0 : (l == 2) ? hb1 : hb0);
    u16* Hout = (l & 1) ? hb1 : hb0;
    int K = (l == 0) ? I_ : H_;
    for (int t0 = 0; t0 < T_; t0 += Tc) {
      gemm_ws<128><<<dim3((B_ * Tc) / 128, G_ / 128), dim3(256), 0, stream>>>(
          Ain, wihH[l], wihL[l], bsum[l], xpb, K, tcl, t0, G_);
      lstm_scan<<<dim3(B_), dim3(512), 0, stream>>>(whhH[l], xpb, Hout, cst, hst, Tc, t0);
    }
  }

  // output projection: [BT,256] x [64,256]^T -> d_out [BT,64]
  gemm_ws<64><<<dim3(BT_ / 128, 1), dim3(256), 0, stream>>>(
      hb1, owH, owL, outb, (float*)d_out, H_, 9, 0, I_);
}

// Round 6
// 5316.915 us; speedup vs baseline: 1.4018x; 1.0059x over previous
//
#include <hip/hip_runtime.h>

typedef unsigned short u16;
typedef unsigned int   u32;
typedef _Float16 f16;
typedef _Float16 half2v __attribute__((ext_vector_type(2)));
typedef _Float16 half8v __attribute__((ext_vector_type(8)));
typedef float float4v __attribute__((ext_vector_type(4)));

#define B_  256
#define T_  512
#define I_  64
#define H_  256
#define G_  1024   // 4*H
#define BT_ (B_*T_)

static __device__ __forceinline__ float fdot2u(u32 a, u32 b, float c) {
#if defined(__has_builtin) && __has_builtin(__builtin_amdgcn_fdot2)
  return __builtin_amdgcn_fdot2(__builtin_bit_cast(half2v, a),
                                __builtin_bit_cast(half2v, b), c, false);
#else
  half2v av = __builtin_bit_cast(half2v, a), bv = __builtin_bit_cast(half2v, b);
  return c + (float)av.x * (float)bv.x + (float)av.y * (float)bv.y;
#endif
}

static __device__ __forceinline__ float sig_(float x) {
  return 1.0f / (1.0f + __expf(-x));
}
static __device__ __forceinline__ float tanh_(float x) {
  // tanh(x) = 2*sigmoid(2x) - 1; saturates correctly for |x| large (exp->0/inf)
  return 2.0f * sig_(2.0f * x) - 1.0f;
}

// ---------------- small prep kernels ----------------

__global__ void cvt_f16(const float* __restrict__ in, u16* __restrict__ out, int n) {
  int i = blockIdx.x * blockDim.x + threadIdx.x;
  if (i < n) out[i] = __builtin_bit_cast(u16, (f16)in[i]);
}

__global__ void split_w(const float* __restrict__ w, u16* __restrict__ hi,
                        u16* __restrict__ lo, int n) {
  int i = blockIdx.x * blockDim.x + threadIdx.x;
  if (i < n) {
    float v = w[i];
    f16 h = (f16)v;
    float r = v - (float)h;
    hi[i] = __builtin_bit_cast(u16, h);
    lo[i] = __builtin_bit_cast(u16, (f16)r);
  }
}

__global__ void bias_sum(const float* __restrict__ a, const float* __restrict__ b,
                         float* __restrict__ o, int n) {
  int i = blockIdx.x * blockDim.x + threadIdx.x;
  if (i < n) o[i] = a[i] + b[i];
}

// ---------------- f16 MFMA GEMM with weight hi/lo split ----------------
// C[m][n] = sum_k A[m][k] * (Bh[n][k] + Bl[n][k]) + bias[n]
// A rows are remapped: chunk-local row m -> global row (m>>tcl)*T_ + t0 + (m & (Tc-1))
template<int BN>
__global__ __launch_bounds__(256) void gemm_ws(
    const u16* __restrict__ A, const u16* __restrict__ Bh, const u16* __restrict__ Bl,
    const float* __restrict__ bias, float* __restrict__ C,
    int K, int tcl, int t0, int N)
{
  constexpr int BM = 128, BK = 64, LDT = 72;  // LDT in f16 units (144 B rows, 16B aligned)
  __shared__ u16 As[BM * LDT];
  __shared__ u16 Bhs[BN * LDT];
  __shared__ u16 Bls[BN * LDT];
  const int tid = threadIdx.x, wave = tid >> 6, lane = tid & 63;
  const int m0 = blockIdx.x * BM, n0 = blockIdx.y * BN;
  constexpr int WNT = BN / 32;          // n-tiles per wave (4 for BN=128, 2 for BN=64)
  const int wm0 = (wave >> 1) * 64, wn0 = (wave & 1) * (BN / 2);
  const int tcmask = (1 << tcl) - 1;
  float4v acc[4][WNT];
  for (int i = 0; i < 4; i++)
    for (int j = 0; j < WNT; j++) acc[i][j] = (float4v){0.f, 0.f, 0.f, 0.f};
  const int lrow = lane & 15, lk = (lane >> 4) * 8;

  for (int k0 = 0; k0 < K; k0 += BK) {
    __syncthreads();
    // stage A: 128 rows x 64 f16 (8x 16B units per row)
#pragma unroll
    for (int i = 0; i < 4; i++) {
      int idx = tid + i * 256, row = idx >> 3, u = idx & 7;
      int m = m0 + row;
      int rg = (m >> tcl) * T_ + t0 + (m & tcmask);
      *(uint4*)(As + row * LDT + u * 8) =
          *(const uint4*)(A + (size_t)rg * K + k0 + u * 8);
    }
#pragma unroll
    for (int i = 0; i < WNT; i++) {
      int idx = tid + i * 256, row = idx >> 3, u = idx & 7;
      size_t go = (size_t)(n0 + row) * K + k0 + u * 8;
      *(uint4*)(Bhs + row * LDT + u * 8) = *(const uint4*)(Bh + go);
      *(uint4*)(Bls + row * LDT + u * 8) = *(const uint4*)(Bl + go);
    }
    __syncthreads();
#pragma unroll
    for (int ks = 0; ks < 2; ++ks) {
      int col = ks * 32 + lk;
      half8v af[4];
#pragma unroll
      for (int mt = 0; mt < 4; mt++)
        af[mt] = *(const half8v*)(const void*)(As + (wm0 + mt * 16 + lrow) * LDT + col);
#pragma unroll
      for (int nt = 0; nt < WNT; nt++) {
        half8v bhv = *(const half8v*)(const void*)(Bhs + (wn0 + nt * 16 + lrow) * LDT + col);
        half8v blv = *(const half8v*)(const void*)(Bls + (wn0 + nt * 16 + lrow) * LDT + col);
#pragma unroll
        for (int mt = 0; mt < 4; mt++) {
          acc[mt][nt] = __builtin_amdgcn_mfma_f32_16x16x32_f16(af[mt], bhv, acc[mt][nt], 0, 0, 0);
          acc[mt][nt] = __builtin_amdgcn_mfma_f32_16x16x32_f16(af[mt], blv, acc[mt][nt], 0, 0, 0);
        }
      }
    }
  }
  // epilogue: C/D layout col = lane&15, row = (lane>>4)*4 + reg
  const int crow = (lane >> 4) * 4, ccol = lane & 15;
#pragma unroll
  for (int nt = 0; nt < WNT; nt++) {
    int n = n0 + wn0 + nt * 16 + ccol;
    float bv = bias[n];
#pragma unroll
    for (int mt = 0; mt < 4; mt++) {
#pragma unroll
      for (int r = 0; r < 4; r++) {
        int m = m0 + wm0 + mt * 16 + crow + r;
        C[(size_t)m * N + n] = acc[mt][nt][r] + bv;
      }
    }
  }
}

// ---------------- persistent per-batch LSTM scan ----------------
// One block per batch element (256 blocks, 512 threads, 8 waves, 1 block/CU).
// Logical row remap (gate interleave): thread 2m owns rows m (i-gate) and
// m+512 (g-gate); thread 2m+1 owns rows m+256 (f-gate) and m+768 (o-gate).
// So all 4 gate pre-activations of h-index m live in the lane pair (2m,2m+1)
// of ONE wave -> gate exchange is two __shfl_xor(.,1): no gs LDS round-trip,
// gate math spread over all 8 waves, ONE barrier per step (h double-buffered).
// CRITICAL (R2 lesson): weight tails in LDS are indexed by PHYSICAL tid
// (wt + tid*72, wt + (tid+512)*72) regardless of logical row -> byte-identical
// LDS addressing to the proven conflict-free R0 layout.
__global__ __launch_bounds__(512, 1) void lstm_scan(
    const u16* __restrict__ whh, const float* __restrict__ xp,
    u16* __restrict__ hout, float* __restrict__ cst, u16* __restrict__ hst,
    int Tc, int t0)
{
  __shared__ u16 wt[1024 * 72];   // 144 KB: per-row 64-f16 tail (128 B) + 16 B pad
  __shared__ u32 h2s[2][128];     // double-buffered h (256 packed f16 each)
  const int tid = threadIdx.x, b = blockIdx.x;
  const int m = tid >> 1;                      // h-index this lane pair serves
  const int lr0 = m + (tid & 1) * 256;         // even: i-row m; odd: f-row m+256
  const int lr1 = lr0 + 512;                   // even: g-row;   odd: o-row

  uint4 w0q[24], w1q[24];
  const uint4* g0 = (const uint4*)(whh + (size_t)lr0 * 256);
  const uint4* g1 = (const uint4*)(whh + (size_t)lr1 * 256);
#pragma unroll
  for (int i = 0; i < 24; i++) { w0q[i] = g0[i]; w1q[i] = g1[i]; }
#pragma unroll
  for (int i = 0; i < 8; i++) {
    *((uint4*)(wt + (size_t)tid * 72) + i) = g0[24 + i];          // physical slot tid
    *((uint4*)(wt + (size_t)(tid + 512) * 72) + i) = g1[24 + i];  // physical slot tid+512
  }

  float cc = 0.f;
  if (t0 == 0) {
    if (tid < 128) h2s[0][tid] = 0u;
  } else {
    if (!(tid & 1)) cc = cst[(size_t)b * 256 + m];
    if (tid < 128) h2s[0][tid] = ((const u32*)hst)[(size_t)b * 128 + tid];
  }
  __syncthreads();

  const float* xpb = xp + (size_t)b * Tc * 1024;
  float xn0 = xpb[lr0], xn1 = xpb[lr1];
  u16* houtb = hout + (size_t)b * T_ * 256 + (size_t)t0 * 256;
  const uint4* wt0 = (const uint4*)(wt + (size_t)tid * 72);
  const uint4* wt1 = (const uint4*)(wt + (size_t)(tid + 512) * 72);

  for (int tt = 0; tt < Tc; ++tt) {
    const int rp = tt & 1, wp = rp ^ 1;
    float a0 = xn0, a1 = xn1;
    if (tt + 1 < Tc) {
      xn0 = xpb[(size_t)(tt + 1) * 1024 + lr0];
      xn1 = xpb[(size_t)(tt + 1) * 1024 + lr1];
    }
    const uint4* hq = (const uint4*)h2s[rp];
#pragma unroll
    for (int kc = 0; kc < 24; ++kc) {
      uint4 hv = hq[kc];
      uint4 w0 = w0q[kc], w1 = w1q[kc];
      a0 = fdot2u(w0.x, hv.x, a0); a0 = fdot2u(w0.y, hv.y, a0);
      a0 = fdot2u(w0.z, hv.z, a0); a0 = fdot2u(w0.w, hv.w, a0);
      a1 = fdot2u(w1.x, hv.x, a1); a1 = fdot2u(w1.y, hv.y, a1);
      a1 = fdot2u(w1.z, hv.z, a1); a1 = fdot2u(w1.w, hv.w, a1);
    }
#pragma unroll
    for (int kc = 0; kc < 8; ++kc) {
      uint4 hv = hq[24 + kc];
      uint4 w0 = wt0[kc], w1 = wt1[kc];
      a0 = fdot2u(w0.x, hv.x, a0); a0 = fdot2u(w0.y, hv.y, a0);
      a0 = fdot2u(w0.z, hv.z, a0); a0 = fdot2u(w0.w, hv.w, a0);
      a1 = fdot2u(w1.x, hv.x, a1); a1 = fdot2u(w1.y, hv.y, a1);
      a1 = fdot2u(w1.z, hv.z, a1); a1 = fdot2u(w1.w, hv.w, a1);
    }
    // gate exchange within lane pair: even has (i,g), odd has (f,o)
    float x0 = __shfl_xor(a0, 1);   // even receives f-pre
    float x1 = __shfl_xor(a1, 1);   // even receives o-pre
    if (!(tid & 1)) {
      float iv = sig_(a0), gv = tanh_(a1), fv = sig_(x0), ov = sig_(x1);
      cc = fv * cc + iv * gv;
      float hv = ov * tanh_(cc);
      u16 hb = __builtin_bit_cast(u16, (f16)hv);
      ((u16*)h2s[wp])[m] = hb;
      houtb[(size_t)tt * 256 + m] = hb;
    }
    __syncthreads();
  }
  if (!(tid & 1)) cst[(size_t)b * 256 + m] = cc;
  if (tid < 128) ((u32*)hst)[(size_t)b * 128 + tid] = h2s[Tc & 1][tid];
}

// ---------------- host ----------------

extern "C" void kernel_launch(void* const* d_in, const int* in_sizes, int n_in,
                              void* d_out, int out_size, void* d_ws, size_t ws_size,
                              hipStream_t stream)
{
  const float* x      = (const float*)d_in[0];
  const float* Wih[4] = {(const float*)d_in[1], (const float*)d_in[5],
                         (const float*)d_in[9], (const float*)d_in[13]};
  const float* Whh[4] = {(const float*)d_in[2], (const float*)d_in[6],
                         (const float*)d_in[10], (const float*)d_in[14]};
  const float* bi[4]  = {(const float*)d_in[3], (const float*)d_in[7],
                         (const float*)d_in[11], (const float*)d_in[15]};
  const float* bh[4]  = {(const float*)d_in[4], (const float*)d_in[8],
                         (const float*)d_in[12], (const float*)d_in[16]};
  const float* outW   = (const float*)d_in[17];
  const float* outb   = (const float*)d_in[18];

  char* ws = (char*)d_ws;
  size_t off = 0;
  auto alc = [&](size_t bytes) -> char* {
    char* p = ws + off;
    off = (off + bytes + 255) & ~(size_t)255;
    return p;
  };

  u16* xf  = (u16*)alc((size_t)BT_ * I_ * 2);
  u16* hb0 = (u16*)alc((size_t)BT_ * H_ * 2);
  u16* hb1 = (u16*)alc((size_t)BT_ * H_ * 2);
  int wihn[4] = {G_ * I_, G_ * H_, G_ * H_, G_ * H_};
  u16 *wihH[4], *wihL[4], *whhH[4];
  float* bsum[4];
  for (int l = 0; l < 4; l++) {
    wihH[l] = (u16*)alc((size_t)wihn[l] * 2);
    wihL[l] = (u16*)alc((size_t)wihn[l] * 2);
    whhH[l] = (u16*)alc((size_t)G_ * H_ * 2);
    bsum[l] = (float*)alc((size_t)G_ * 4);
  }
  u16* owH = (u16*)alc((size_t)I_ * H_ * 2);
  u16* owL = (u16*)alc((size_t)I_ * H_ * 2);
  float* cst = (float*)alc((size_t)B_ * H_ * 4);
  u16*   hst = (u16*)alc((size_t)B_ * H_ * 2);

  // choose time-chunk so the fp32 xp buffer fits in the remaining workspace
  int Tc = T_;
  while (Tc > 16 && off + (size_t)B_ * Tc * G_ * 4 + 4096 > ws_size) Tc >>= 1;
  float* xpb = (float*)alc((size_t)B_ * Tc * G_ * 4);
  int tcl = 0;
  while ((1 << tcl) < Tc) tcl++;

  // prep: conversions / splits / bias sums
  {
    int n = BT_ * I_;
    cvt_f16<<<dim3((n + 255) / 256), dim3(256), 0, stream>>>(x, xf, n);
  }
  for (int l = 0; l < 4; l++) {
    split_w<<<dim3((wihn[l] + 255) / 256), dim3(256), 0, stream>>>(Wih[l], wihH[l], wihL[l], wihn[l]);
    cvt_f16<<<dim3((G_ * H_ + 255) / 256), dim3(256), 0, stream>>>(Whh[l], whhH[l], G_ * H_);
    bias_sum<<<dim3(4), dim3(256), 0, stream>>>(bi[l], bh[l], bsum[l], G_);
  }
  split_w<<<dim3((I_ * H_ + 255) / 256), dim3(256), 0, stream>>>(outW, owH, owL, I_ * H_);

  // 4 LSTM layers, chunked over T
  for (int l = 0; l < 4; l++) {
    const u16* Ain = (l == 0) ? xf : ((l == 1) ? hb0 : (l == 2) ? hb1 : hb0);
    u16* Hout = (l & 1) ? hb1 : hb0;
    int K = (l == 0) ? I_ : H_;
    for (int t0 = 0; t0 < T_; t0 += Tc) {
      gemm_ws<128><<<dim3((B_ * Tc) / 128, G_ / 128), dim3(256), 0, stream>>>(
          Ain, wihH[l], wihL[l], bsum[l], xpb, K, tcl, t0, G_);
      lstm_scan<<<dim3(B_), dim3(512), 0, stream>>>(whhH[l], xpb, Hout, cst, hst, Tc, t0);
    }
  }

  // output projection: [BT,256] x [64,256]^T -> d_out [BT,64]
  gemm_ws<64><<<dim3(BT_ / 128, 1), dim3(256), 0, stream>>>(
      hb1, owH, owL, outb, (float*)d_out, H_, 9, 0, I_);
}

// Round 8
// 4914.372 us; speedup vs baseline: 1.5167x; 1.0819x over previous
//
#include <hip/hip_runtime.h>

typedef unsigned short u16;
typedef unsigned int   u32;
typedef _Float16 f16;
typedef _Float16 half2v __attribute__((ext_vector_type(2)));
typedef _Float16 half8v __attribute__((ext_vector_type(8)));
typedef float float4v __attribute__((ext_vector_type(4)));

#define B_  256
#define T_  512
#define I_  64
#define H_  256
#define G_  1024   // 4*H
#define BT_ (B_*T_)

static __device__ __forceinline__ float fdot2u(u32 a, u32 b, float c) {
#if defined(__has_builtin) && __has_builtin(__builtin_amdgcn_fdot2)
  return __builtin_amdgcn_fdot2(__builtin_bit_cast(half2v, a),
                                __builtin_bit_cast(half2v, b), c, false);
#else
  half2v av = __builtin_bit_cast(half2v, a), bv = __builtin_bit_cast(half2v, b);
  return c + (float)av.x * (float)bv.x + (float)av.y * (float)bv.y;
#endif
}

static __device__ __forceinline__ float sig_(float x) {
  return 1.0f / (1.0f + __expf(-x));
}
static __device__ __forceinline__ float tanh_(float x) {
  float ax = fminf(fabsf(x), 15.0f);
  float e  = __expf(2.0f * ax);
  float t  = (e - 1.0f) / (e + 1.0f);
  return copysignf(t, x);
}

// ---------------- small prep kernels ----------------

__global__ void cvt_f16(const float* __restrict__ in, u16* __restrict__ out, int n) {
  int i = blockIdx.x * blockDim.x + threadIdx.x;
  if (i < n) out[i] = __builtin_bit_cast(u16, (f16)in[i]);
}

__global__ void split_w(const float* __restrict__ w, u16* __restrict__ hi,
                        u16* __restrict__ lo, int n) {
  int i = blockIdx.x * blockDim.x + threadIdx.x;
  if (i < n) {
    float v = w[i];
    f16 h = (f16)v;
    float r = v - (float)h;
    hi[i] = __builtin_bit_cast(u16, h);
    lo[i] = __builtin_bit_cast(u16, (f16)r);
  }
}

__global__ void bias_sum(const float* __restrict__ a, const float* __restrict__ b,
                         float* __restrict__ o, int n) {
  int i = blockIdx.x * blockDim.x + threadIdx.x;
  if (i < n) o[i] = a[i] + b[i];
}

// ---------------- f16 MFMA GEMM with weight hi/lo split ----------------
// C[m][n] = sum_k A[m][k] * (Bh[n][k] + Bl[n][k]) + bias[n]
// A rows are remapped: chunk-local row m -> global row (m>>tcl)*T_ + t0 + (m & (Tc-1))
template<int BN>
__global__ __launch_bounds__(256) void gemm_ws(
    const u16* __restrict__ A, const u16* __restrict__ Bh, const u16* __restrict__ Bl,
    const float* __restrict__ bias, float* __restrict__ C,
    int K, int tcl, int t0, int N)
{
  constexpr int BM = 128, BK = 64, LDT = 72;  // LDT in f16 units (144 B rows, 16B aligned)
  __shared__ u16 As[BM * LDT];
  __shared__ u16 Bhs[BN * LDT];
  __shared__ u16 Bls[BN * LDT];
  const int tid = threadIdx.x, wave = tid >> 6, lane = tid & 63;
  const int m0 = blockIdx.x * BM, n0 = blockIdx.y * BN;
  constexpr int WNT = BN / 32;          // n-tiles per wave (4 for BN=128, 2 for BN=64)
  const int wm0 = (wave >> 1) * 64, wn0 = (wave & 1) * (BN / 2);
  const int tcmask = (1 << tcl) - 1;
  float4v acc[4][WNT];
  for (int i = 0; i < 4; i++)
    for (int j = 0; j < WNT; j++) acc[i][j] = (float4v){0.f, 0.f, 0.f, 0.f};
  const int lrow = lane & 15, lk = (lane >> 4) * 8;

  for (int k0 = 0; k0 < K; k0 += BK) {
    __syncthreads();
    // stage A: 128 rows x 64 f16 (8x 16B units per row)
#pragma unroll
    for (int i = 0; i < 4; i++) {
      int idx = tid + i * 256, row = idx >> 3, u = idx & 7;
      int m = m0 + row;
      int rg = (m >> tcl) * T_ + t0 + (m & tcmask);
      *(uint4*)(As + row * LDT + u * 8) =
          *(const uint4*)(A + (size_t)rg * K + k0 + u * 8);
    }
#pragma unroll
    for (int i = 0; i < WNT; i++) {
      int idx = tid + i * 256, row = idx >> 3, u = idx & 7;
      size_t go = (size_t)(n0 + row) * K + k0 + u * 8;
      *(uint4*)(Bhs + row * LDT + u * 8) = *(const uint4*)(Bh + go);
      *(uint4*)(Bls + row * LDT + u * 8) = *(const uint4*)(Bl + go);
    }
    __syncthreads();
#pragma unroll
    for (int ks = 0; ks < 2; ++ks) {
      int col = ks * 32 + lk;
      half8v af[4];
#pragma unroll
      for (int mt = 0; mt < 4; mt++)
        af[mt] = *(const half8v*)(const void*)(As + (wm0 + mt * 16 + lrow) * LDT + col);
#pragma unroll
      for (int nt = 0; nt < WNT; nt++) {
        half8v bhv = *(const half8v*)(const void*)(Bhs + (wn0 + nt * 16 + lrow) * LDT + col);
        half8v blv = *(const half8v*)(const void*)(Bls + (wn0 + nt * 16 + lrow) * LDT + col);
#pragma unroll
        for (int mt = 0; mt < 4; mt++) {
          acc[mt][nt] = __builtin_amdgcn_mfma_f32_16x16x32_f16(af[mt], bhv, acc[mt][nt], 0, 0, 0);
          acc[mt][nt] = __builtin_amdgcn_mfma_f32_16x16x32_f16(af[mt], blv, acc[mt][nt], 0, 0, 0);
        }
      }
    }
  }
  // epilogue: C/D layout col = lane&15, row = (lane>>4)*4 + reg
  const int crow = (lane >> 4) * 4, ccol = lane & 15;
#pragma unroll
  for (int nt = 0; nt < WNT; nt++) {
    int n = n0 + wn0 + nt * 16 + ccol;
    float bv = bias[n];
#pragma unroll
    for (int mt = 0; mt < 4; mt++) {
#pragma unroll
      for (int r = 0; r < 4; r++) {
        int m = m0 + wm0 + mt * 16 + crow + r;
        C[(size_t)m * N + n] = acc[mt][nt][r] + bv;
      }
    }
  }
}

// ---------------- persistent per-batch LSTM scan ----------------
// One block per batch element (256 blocks, 512 threads, 8 waves, 1 block/CU).
// Thread tid owns rows tid and tid+512 of Whh[1024][256] (f16):
//   elems [0,192) in registers (192 VGPRs), elems [192,256) in LDS (144 KB).
// Per step: g[j] = xp[b][t][j] + dot(Whh[j,:], h) via v_dot2_f32_f16;
// threads <256 apply gates, update c (fp32 reg) / h (f16 in LDS + global).
// NOTE (R1-R7): six structural perturbations (multi-acc chains, pair/quad
// gate interleave with 1 barrier, 1024-thread reg rebalance, readlane-SGPR
// h-broadcast, LDS-tail shrink) all measured >= this layout. Step time
// ~= VALU issue (~2.5k cyc) + LDS pipe (~2.6k cyc), phases lockstep.
__global__ __launch_bounds__(512, 2) void lstm_scan(
    const u16* __restrict__ whh, const float* __restrict__ xp,
    u16* __restrict__ hout, float* __restrict__ cst, u16* __restrict__ hst,
    int Tc, int t0)
{
  __shared__ u16 wt[1024 * 72];   // 144 KB: per-row 64-f16 tail (128 B) + 16 B pad
  __shared__ float gs[1024];      // gate pre-activations
  __shared__ u32 h2s[128];        // h as 256 packed f16
  const int tid = threadIdx.x, b = blockIdx.x;
  const int r0 = tid, r1 = tid + 512;

  uint4 w0q[24], w1q[24];
  const uint4* g0 = (const uint4*)(whh + (size_t)r0 * 256);
  const uint4* g1 = (const uint4*)(whh + (size_t)r1 * 256);
#pragma unroll
  for (int i = 0; i < 24; i++) { w0q[i] = g0[i]; w1q[i] = g1[i]; }
#pragma unroll
  for (int i = 0; i < 8; i++) {
    *((uint4*)(wt + (size_t)r0 * 72) + i) = g0[24 + i];
    *((uint4*)(wt + (size_t)r1 * 72) + i) = g1[24 + i];
  }

  float cc = 0.f;
  if (t0 == 0) {
    if (tid < 128) h2s[tid] = 0u;
  } else {
    if (tid < 256) cc = cst[(size_t)b * 256 + tid];
    if (tid < 128) h2s[tid] = ((const u32*)hst)[(size_t)b * 128 + tid];
  }
  __syncthreads();

  const float* xpb = xp + (size_t)b * Tc * 1024;
  float xn0 = xpb[r0], xn1 = xpb[r1];
  u16* houtb = hout + (size_t)b * T_ * 256 + (size_t)t0 * 256;

  for (int tt = 0; tt < Tc; ++tt) {
    float a0 = xn0, a1 = xn1;
    if (tt + 1 < Tc) {
      xn0 = xpb[(size_t)(tt + 1) * 1024 + r0];
      xn1 = xpb[(size_t)(tt + 1) * 1024 + r1];
    }
    const uint4* hq = (const uint4*)h2s;
#pragma unroll
    for (int kc = 0; kc < 24; ++kc) {
      uint4 hv = hq[kc];
      uint4 w0 = w0q[kc], w1 = w1q[kc];
      a0 = fdot2u(w0.x, hv.x, a0); a0 = fdot2u(w0.y, hv.y, a0);
      a0 = fdot2u(w0.z, hv.z, a0); a0 = fdot2u(w0.w, hv.w, a0);
      a1 = fdot2u(w1.x, hv.x, a1); a1 = fdot2u(w1.y, hv.y, a1);
      a1 = fdot2u(w1.z, hv.z, a1); a1 = fdot2u(w1.w, hv.w, a1);
    }
    const uint4* wt0 = (const uint4*)(wt + (size_t)r0 * 72);
    const uint4* wt1 = (const uint4*)(wt + (size_t)r1 * 72);
#pragma unroll
    for (int kc = 0; kc < 8; ++kc) {
      uint4 hv = hq[24 + kc];
      uint4 w0 = wt0[kc], w1 = wt1[kc];
      a0 = fdot2u(w0.x, hv.x, a0); a0 = fdot2u(w0.y, hv.y, a0);
      a0 = fdot2u(w0.z, hv.z, a0); a0 = fdot2u(w0.w, hv.w, a0);
      a1 = fdot2u(w1.x, hv.x, a1); a1 = fdot2u(w1.y, hv.y, a1);
      a1 = fdot2u(w1.z, hv.z, a1); a1 = fdot2u(w1.w, hv.w, a1);
    }
    gs[r0] = a0; gs[r1] = a1;
    __syncthreads();
    if (tid < 256) {
      float gi = gs[tid], gf = gs[tid + 256], gg = gs[tid + 512], go = gs[tid + 768];
      float iv = sig_(gi), fv = sig_(gf), ov = sig_(go), gv = tanh_(gg);
      cc = fv * cc + iv * gv;
      float hv = ov * tanh_(cc);
      u16 hb = __builtin_bit_cast(u16, (f16)hv);
      ((u16*)h2s)[tid] = hb;
      houtb[(size_t)tt * 256 + tid] = hb;
    }
    __syncthreads();
  }
  if (tid < 256) cst[(size_t)b * 256 + tid] = cc;
  if (tid < 128) ((u32*)hst)[(size_t)b * 128 + tid] = h2s[tid];
}

// ---------------- host ----------------

extern "C" void kernel_launch(void* const* d_in, const int* in_sizes, int n_in,
                              void* d_out, int out_size, void* d_ws, size_t ws_size,
                              hipStream_t stream)
{
  const float* x      = (const float*)d_in[0];
  const float* Wih[4] = {(const float*)d_in[1], (const float*)d_in[5],
                         (const float*)d_in[9], (const float*)d_in[13]};
  const float* Whh[4] = {(const float*)d_in[2], (const float*)d_in[6],
                         (const float*)d_in[10], (const float*)d_in[14]};
  const float* bi[4]  = {(const float*)d_in[3], (const float*)d_in[7],
                         (const float*)d_in[11], (const float*)d_in[15]};
  const float* bh[4]  = {(const float*)d_in[4], (const float*)d_in[8],
                         (const float*)d_in[12], (const float*)d_in[16]};
  const float* outW   = (const float*)d_in[17];
  const float* outb   = (const float*)d_in[18];

  char* ws = (char*)d_ws;
  size_t off = 0;
  auto alc = [&](size_t bytes) -> char* {
    char* p = ws + off;
    off = (off + bytes + 255) & ~(size_t)255;
    return p;
  };

  u16* xf  = (u16*)alc((size_t)BT_ * I_ * 2);
  u16* hb0 = (u16*)alc((size_t)BT_ * H_ * 2);
  u16* hb1 = (u16*)alc((size_t)BT_ * H_ * 2);
  int wihn[4] = {G_ * I_, G_ * H_, G_ * H_, G_ * H_};
  u16 *wihH[4], *wihL[4], *whhH[4];
  float* bsum[4];
  for (int l = 0; l < 4; l++) {
    wihH[l] = (u16*)alc((size_t)wihn[l] * 2);
    wihL[l] = (u16*)alc((size_t)wihn[l] * 2);
    whhH[l] = (u16*)alc((size_t)G_ * H_ * 2);
    bsum[l] = (float*)alc((size_t)G_ * 4);
  }
  u16* owH = (u16*)alc((size_t)I_ * H_ * 2);
  u16* owL = (u16*)alc((size_t)I_ * H_ * 2);
  float* cst = (float*)alc((size_t)B_ * H_ * 4);
  u16*   hst = (u16*)alc((size_t)B_ * H_ * 2);

  // choose time-chunk so the fp32 xp buffer fits in the remaining workspace
  int Tc = T_;
  while (Tc > 16 && off + (size_t)B_ * Tc * G_ * 4 + 4096 > ws_size) Tc >>= 1;
  float* xpb = (float*)alc((size_t)B_ * Tc * G_ * 4);
  int tcl = 0;
  while ((1 << tcl) < Tc) tcl++;

  // prep: conversions / splits / bias sums
  {
    int n = BT_ * I_;
    cvt_f16<<<dim3((n + 255) / 256), dim3(256), 0, stream>>>(x, xf, n);
  }
  for (int l = 0; l < 4; l++) {
    split_w<<<dim3((wihn[l] + 255) / 256), dim3(256), 0, stream>>>(Wih[l], wihH[l], wihL[l], wihn[l]);
    cvt_f16<<<dim3((G_ * H_ + 255) / 256), dim3(256), 0, stream>>>(Whh[l], whhH[l], G_ * H_);
    bias_sum<<<dim3(4), dim3(256), 0, stream>>>(bi[l], bh[l], bsum[l], G_);
  }
  split_w<<<dim3((I_ * H_ + 255) / 256), dim3(256), 0, stream>>>(outW, owH, owL, I_ * H_);

  // 4 LSTM layers, chunked over T
  for (int l = 0; l < 4; l++) {
    const u16* Ain = (l == 0) ? xf : ((l == 1) ? hb0 : (l == 2) ? hb1 : hb0);
    u16* Hout = (l & 1) ? hb1 : hb0;
    int K = (l == 0) ? I_ : H_;
    for (int t0 = 0; t0 < T_; t0 += Tc) {
      gemm_ws<128><<<dim3((B_ * Tc) / 128, G_ / 128), dim3(256), 0, stream>>>(
          Ain, wihH[l], wihL[l], bsum[l], xpb, K, tcl, t0, G_);
      lstm_scan<<<dim3(B_), dim3(512), 0, stream>>>(whhH[l], xpb, Hout, cst, hst, Tc, t0);
    }
  }

  // output projection: [BT,256] x [64,256]^T -> d_out [BT,64]
  gemm_ws<64><<<dim3(BT_ / 128, 1), dim3(256), 0, stream>>>(
      hb1, owH, owL, outb, (float*)d_out, H_, 9, 0, I_);
}